// Round 4
// baseline (169.335 us; speedup 1.0000x reference)
//
#include <hip/hip_runtime.h>
#include <math.h>

#define BB 32
#define NN 8192
#define WW 256
#define RR 4
#define CDIM (3*WW + RR + 3)   // 775
#define EPSF 1e-8f

#define K_SEL 128
#define CAP   256

typedef float floatx4 __attribute__((ext_vector_type(4)));

// ---- workspace layout (float offsets) ----
#define O_KEY    0                      // B*W
#define O_ERASE  (O_KEY   + BB*WW)
#define O_ADD    (O_ERASE + BB*WW)
#define O_FG     (O_ADD   + BB*WW)      // B*R
#define O_KN     (O_FG    + BB*RR)
#define O_BETA   (O_KN    + BB)
#define O_AG     (O_BETA  + BB)
#define O_WG     (O_AG    + BB)
#define O_S      (O_WG    + BB)         // B*N : holds p = exp(score)
#define O_PHI    (O_S     + BB*NN)      // B*N
#define O_ALLOC  (O_PHI   + BB*NN)      // B*N
#define O_USC    (O_ALLOC + BB*NN)      // B*N
#define O_SUM    (O_USC   + BB*NN)      // B   : softmax denom accumulator

__device__ __forceinline__ float sigmoidf_(float x) { return 1.0f / (1.0f + expf(-x)); }

// ---------------- kernel 1: parse controls per batch; zero sums ----------------
__global__ __launch_bounds__(256) void prep_kernel(const float* __restrict__ controls,
                                                   float* __restrict__ ws) {
    int b = blockIdx.x;
    int t = threadIdx.x;
    const float* c = controls + (size_t)b * CDIM;
    float k = c[t];
    ws[O_KEY   + b*WW + t] = k;
    ws[O_ERASE + b*WW + t] = sigmoidf_(c[WW + t]);
    ws[O_ADD   + b*WW + t] = c[2*WW + t];

    __shared__ float red[256];
    red[t] = k * k;
    __syncthreads();
    for (int s = 128; s > 0; s >>= 1) {
        if (t < s) red[t] += red[t + s];
        __syncthreads();
    }
    if (t < RR) ws[O_FG + b*RR + t] = sigmoidf_(c[3*WW + t]);
    if (t == 0) {
        ws[O_KN + b] = sqrtf(red[0]);
        float x = c[3*WW + RR];
        float sp = fmaxf(x, 0.0f) + log1pf(expf(-fabsf(x)));  // stable softplus
        ws[O_BETA + b] = 1.0f + sp;
        ws[O_AG + b] = sigmoidf_(c[3*WW + RR + 1]);
        ws[O_WG + b] = sigmoidf_(c[3*WW + RR + 2]);
        ws[O_SUM + b] = 0.0f;
    }
}

// ---------------- kernel 2: phi, u_scaled; zero alloc ----------------
__global__ __launch_bounds__(256) void phiu_kernel(const float* __restrict__ rw,
                                                   const float* __restrict__ us,
                                                   const float* __restrict__ pw,
                                                   float* __restrict__ ws) {
    int gid = blockIdx.x * 256 + threadIdx.x;
    int b = gid >> 13;
    int n = gid & (NN - 1);
    float phi = 1.0f;
#pragma unroll
    for (int r = 0; r < RR; r++) {
        float fg = ws[O_FG + b*RR + r];
        phi *= (1.0f - fg * rw[((size_t)(b*RR + r)) * NN + n]);
    }
    float u0 = us[gid];
    float u = (u0 + pw[gid] * (1.0f - u0)) * phi;
    float usc = u * (1.0f - EPSF) + EPSF;   // strictly positive, <= 1
    ws[O_PHI   + gid] = phi;
    ws[O_USC   + gid] = usc;
    ws[O_ALLOC + gid] = 0.0f;               // scatter fills only top-K later
}

// -------- kernel 3: top-K smallest u -> allocation weights --------
__global__ __launch_bounds__(1024) void topk_kernel(float* __restrict__ ws) {
    __shared__ unsigned hist[4096];            // 16 KB
    __shared__ unsigned long long cand[CAP];   //  2 KB
    __shared__ unsigned uscan0[1024];          //  4 KB
    __shared__ unsigned uscan1[1024];          //  4 KB
    __shared__ int selbin;
    __shared__ unsigned ccnt;

    int b = blockIdx.x, t = threadIdx.x;
    const float* u = ws + O_USC + (size_t)b * NN;

    for (int i = t; i < 4096; i += 1024) hist[i] = 0;
    if (t == 0) { selbin = 0x7FFFFFFF; ccnt = 0; }
    __syncthreads();

    unsigned fb[8];
#pragma unroll
    for (int q = 0; q < 8; q++) {
        fb[q] = __float_as_uint(u[t + q*1024]);   // positive floats: bits monotone
        atomicAdd(&hist[fb[q] >> 19], 1u);        // usc<=1 -> bin < 4096
    }
    __syncthreads();

    // cumulative over 4096 bins (4 bins/thread + 1024-scan)
    unsigned h0 = hist[4*t], h1 = hist[4*t+1], h2 = hist[4*t+2], h3 = hist[4*t+3];
    unsigned tot = h0 + h1 + h2 + h3;
    unsigned *a0 = uscan0, *a1 = uscan1;
    a0[t] = tot;
    __syncthreads();
    for (int off = 1; off < 1024; off <<= 1) {
        unsigned v = a0[t];
        if (t >= off) v += a0[t - off];
        a1[t] = v;
        __syncthreads();
        unsigned* tmp = a0; a0 = a1; a1 = tmp;
    }
    unsigned excl = (t == 0) ? 0u : a0[t - 1];
    {
        unsigned c = excl;
        unsigned hh[4] = {h0, h1, h2, h3};
#pragma unroll
        for (int j = 0; j < 4; j++) {
            c += hh[j];
            if (c >= K_SEL) { atomicMin(&selbin, 4*t + j); break; }
        }
    }
    __syncthreads();
    int Bsel = selbin;

    // collect candidates: the smallest cum[Bsel] elements (~K_SEL+bin overshoot)
#pragma unroll
    for (int q = 0; q < 8; q++) {
        if ((int)(fb[q] >> 19) <= Bsel) {
            unsigned pos = atomicAdd(&ccnt, 1u);
            if (pos < CAP)
                cand[pos] = (((unsigned long long)fb[q]) << 32) | (unsigned)(t + q*1024);
        }
    }
    __syncthreads();
    unsigned cnt = min(ccnt, (unsigned)CAP);
    if (t >= cnt && t < CAP) cand[t] = 0x3F800000FFFFFFFFull;  // (1.0f, ~0) pad
    __syncthreads();

    // bitonic sort CAP keys, ascending on (value_bits, idx) -> stable argsort
    for (int k = 2; k <= CAP; k <<= 1) {
        for (int j = k >> 1; j > 0; j >>= 1) {
            if (t < CAP) {
                int l = t ^ j;
                if (l > t) {
                    unsigned long long x = cand[t], y = cand[l];
                    bool asc = ((t & k) == 0);
                    if ((x > y) == asc) { cand[t] = y; cand[l] = x; }
                }
            }
            __syncthreads();
        }
    }

    // exclusive cumulative product of sorted values (first CAP threads)
    float v = 1.0f;
    if (t < CAP) v = __uint_as_float((unsigned)(cand[t] >> 32));
    float *f0 = (float*)uscan0, *f1 = (float*)uscan1;
    if (t < CAP) f0[t] = v;
    __syncthreads();
    for (int off = 1; off < CAP; off <<= 1) {
        float x = 0.0f;
        if (t < CAP) { x = f0[t]; if (t >= off) x *= f0[t - off]; }
        __syncthreads();
        if (t < CAP) f1[t] = x;
        __syncthreads();
        float* tmp = f0; f0 = f1; f1 = tmp;
    }
    if (t < CAP) {
        float pre = (t == 0) ? 1.0f : f0[t - 1];
        unsigned idx = (unsigned)(cand[t] & 0xFFFFFFFFull);
        if (idx < NN)
            ws[O_ALLOC + (size_t)b * NN + idx] = (1.0f - v) * pre;
    }
}

// ------- kernel 4: dots + row norms -> p = exp(beta*cossim); sum(p) -------
__global__ __launch_bounds__(256) void dots_kernel(const float* __restrict__ mem,
                                                   float* __restrict__ ws) {
    int b  = blockIdx.x >> 7;
    int rb = (blockIdx.x & 127) << 6;
    int wave = threadIdx.x >> 6;
    int lane = threadIdx.x & 63;
    int g  = lane >> 4;       // 4 row-groups per wave
    int li = lane & 15;       // 16 lanes per row

    float4 k4[4];
#pragma unroll
    for (int k = 0; k < 4; k++)
        k4[k] = ((const float4*)(ws + O_KEY + b*WW))[li + k*16];
    float kn   = ws[O_KN + b];
    float beta = ws[O_BETA + b];

    float psum = 0.0f;
#pragma unroll
    for (int p = 0; p < 4; p++) {
        int n = rb + wave*16 + p*4 + g;
        const float4* mrow = (const float4*)(mem + ((size_t)b * NN + n) * WW);
        float dot = 0.0f, nn2 = 0.0f;
#pragma unroll
        for (int k = 0; k < 4; k++) {
            float4 m = mrow[li + k*16];
            dot += m.x*k4[k].x + m.y*k4[k].y + m.z*k4[k].z + m.w*k4[k].w;
            nn2 += m.x*m.x + m.y*m.y + m.z*m.z + m.w*m.w;
        }
#pragma unroll
        for (int off = 8; off > 0; off >>= 1) {
            dot += __shfl_xor(dot, off, 64);
            nn2 += __shfl_xor(nn2, off, 64);
        }
        if (li == 0) {
            float pv = expf(dot / (kn * sqrtf(nn2) + EPSF) * beta);
            ws[O_S + (size_t)b * NN + n] = pv;
            psum += pv;
        }
    }
    __shared__ float red[16];
    if (li == 0) red[wave*4 + g] = psum;
    __syncthreads();
    if (threadIdx.x == 0) {
        float s = 0.0f;
#pragma unroll
        for (int i = 0; i < 16; i++) s += red[i];
        atomicAdd(&ws[O_SUM + b], s);
    }
}

// ---------------- kernel 5: fused erase/add update (reverse order) ----------------
__global__ __launch_bounds__(256) void update_kernel(const float* __restrict__ mem,
                                                     const float* __restrict__ ws,
                                                     float* __restrict__ out) {
    int bid = gridDim.x - 1 - blockIdx.x;     // reverse: reuse L3-resident tail of mem
    int b  = bid >> 7;
    int rb = (bid & 127) << 6;
    int wave = threadIdx.x >> 6, lane = threadIdx.x & 63;
    float4 e4 = ((const float4*)(ws + O_ERASE + b*WW))[lane];
    float4 a4 = ((const float4*)(ws + O_ADD + b*WW))[lane];
    float ag = ws[O_AG + b], wg = ws[O_WG + b];
    float iden = 1.0f / ws[O_SUM + b];
#pragma unroll 4
    for (int it = 0; it < 16; ++it) {
        int n = rb + it*4 + wave;
        size_t row = (size_t)b * NN + n;
        float pv  = ws[O_S + row];
        float al  = ws[O_ALLOC + row];
        float phi = ws[O_PHI + row];
        float cw  = pv * iden;
        float wwt = wg * (ag * al + (1.0f - ag) * cw);
        float4 m = ((const float4*)(mem + row * WW))[lane];
        floatx4 o;
        o.x = m.x * (1.0f - wwt * e4.x) * phi + wwt * a4.x;
        o.y = m.y * (1.0f - wwt * e4.y) * phi + wwt * a4.y;
        o.z = m.z * (1.0f - wwt * e4.z) * phi + wwt * a4.z;
        o.w = m.w * (1.0f - wwt * e4.w) * phi + wwt * a4.w;
        __builtin_nontemporal_store(o, &((floatx4*)(out + row * WW))[lane]);
    }
}

extern "C" void kernel_launch(void* const* d_in, const int* in_sizes, int n_in,
                              void* d_out, int out_size, void* d_ws, size_t ws_size,
                              hipStream_t stream) {
    const float* mem      = (const float*)d_in[0];
    const float* controls = (const float*)d_in[1];
    const float* rw       = (const float*)d_in[2];
    const float* us       = (const float*)d_in[3];
    const float* pw       = (const float*)d_in[4];
    float* out = (float*)d_out;
    float* ws  = (float*)d_ws;

    prep_kernel<<<BB, 256, 0, stream>>>(controls, ws);
    phiu_kernel<<<(BB * NN) / 256, 256, 0, stream>>>(rw, us, pw, ws);
    topk_kernel<<<BB, 1024, 0, stream>>>(ws);
    dots_kernel<<<BB * (NN / 64), 256, 0, stream>>>(mem, ws);
    update_kernel<<<BB * (NN / 64), 256, 0, stream>>>(mem, ws, out);
}

// Round 5
// 144.779 us; speedup vs baseline: 1.1696x; 1.1696x over previous
//
#include <hip/hip_runtime.h>
#include <math.h>

#define BB 32
#define NN 8192
#define WW 256
#define RR 4
#define CDIM (3*WW + RR + 3)   // 775
#define EPSF 1e-8f

#define K_SEL 128
#define CAP   256

typedef float floatx4 __attribute__((ext_vector_type(4)));

// ---- workspace layout (float offsets) ----
#define O_KEY    0                      // B*W
#define O_ERASE  (O_KEY   + BB*WW)
#define O_ADD    (O_ERASE + BB*WW)
#define O_FG     (O_ADD   + BB*WW)      // B*R
#define O_KN     (O_FG    + BB*RR)
#define O_BETA   (O_KN    + BB)
#define O_AG     (O_BETA  + BB)
#define O_WG     (O_AG    + BB)
#define O_S      (O_WG    + BB)         // B*N : p = exp(beta*cossim)
#define O_PHI    (O_S     + BB*NN)      // B*N
#define O_ALLOC  (O_PHI   + BB*NN)      // B*N
#define O_SUM    (O_ALLOC + BB*NN)      // B

__device__ __forceinline__ float sigmoidf_(float x) { return 1.0f / (1.0f + expf(-x)); }

// ---------------- kernel 1: parse controls per batch; zero sums ----------------
__global__ __launch_bounds__(256) void prep_kernel(const float* __restrict__ controls,
                                                   float* __restrict__ ws) {
    int b = blockIdx.x;
    int t = threadIdx.x;
    const float* c = controls + (size_t)b * CDIM;
    float k = c[t];
    ws[O_KEY   + b*WW + t] = k;
    ws[O_ERASE + b*WW + t] = sigmoidf_(c[WW + t]);
    ws[O_ADD   + b*WW + t] = c[2*WW + t];

    __shared__ float red[256];
    red[t] = k * k;
    __syncthreads();
    for (int s = 128; s > 0; s >>= 1) {
        if (t < s) red[t] += red[t + s];
        __syncthreads();
    }
    if (t < RR) ws[O_FG + b*RR + t] = sigmoidf_(c[3*WW + t]);
    if (t == 0) {
        ws[O_KN + b] = sqrtf(red[0]);
        float x = c[3*WW + RR];
        float sp = fmaxf(x, 0.0f) + log1pf(expf(-fabsf(x)));  // stable softplus
        ws[O_BETA + b] = 1.0f + sp;
        ws[O_AG + b] = sigmoidf_(c[3*WW + RR + 1]);
        ws[O_WG + b] = sigmoidf_(c[3*WW + RR + 2]);
        ws[O_SUM + b] = 0.0f;
    }
}

// ------- kernel 2: role-split. blocks 0..31: phi/usc/topk/alloc.
//                   blocks 32..1055: dots -> p, partial softmax sums. -------
__global__ __launch_bounds__(1024) void mid_kernel(const float* __restrict__ mem,
                                                   const float* __restrict__ rw,
                                                   const float* __restrict__ us,
                                                   const float* __restrict__ pw,
                                                   float* __restrict__ ws) {
    __shared__ unsigned hist[4096];            // 16 KB (topk role)
    __shared__ unsigned long long cand[CAP];   //  2 KB
    __shared__ unsigned uscan0[1024];          //  4 KB
    __shared__ unsigned uscan1[1024];          //  4 KB
    __shared__ float    dred[64];              // dots role
    __shared__ int selbin;
    __shared__ unsigned ccnt;

    int t = threadIdx.x;

    if (blockIdx.x < BB) {
        // ================= TOP-K role (one block per batch) =================
        int b = blockIdx.x;
        for (int i = t; i < 4096; i += 1024) hist[i] = 0;
        if (t == 0) { selbin = 0x7FFFFFFF; ccnt = 0; }
        __syncthreads();

        unsigned fb[8];
#pragma unroll
        for (int q = 0; q < 8; q++) {
            int n = t + q * 1024;
            size_t gid = (size_t)b * NN + n;
            float phi = 1.0f;
#pragma unroll
            for (int r = 0; r < RR; r++) {
                float fg = ws[O_FG + b*RR + r];
                phi *= (1.0f - fg * rw[((size_t)(b*RR + r)) * NN + n]);
            }
            float u0 = us[gid];
            float u = (u0 + pw[gid] * (1.0f - u0)) * phi;
            float usc = u * (1.0f - EPSF) + EPSF;   // strictly positive, <= 1
            ws[O_PHI   + gid] = phi;
            ws[O_ALLOC + gid] = 0.0f;               // scatter fills top-K below
            fb[q] = __float_as_uint(usc);           // bits monotone for +floats
            atomicAdd(&hist[fb[q] >> 19], 1u);
        }
        __syncthreads();

        // cumulative over 4096 bins (4 bins/thread + 1024-scan)
        unsigned h0 = hist[4*t], h1 = hist[4*t+1], h2 = hist[4*t+2], h3 = hist[4*t+3];
        unsigned tot = h0 + h1 + h2 + h3;
        unsigned *a0 = uscan0, *a1 = uscan1;
        a0[t] = tot;
        __syncthreads();
        for (int off = 1; off < 1024; off <<= 1) {
            unsigned v = a0[t];
            if (t >= off) v += a0[t - off];
            a1[t] = v;
            __syncthreads();
            unsigned* tmp = a0; a0 = a1; a1 = tmp;
        }
        unsigned excl = (t == 0) ? 0u : a0[t - 1];
        {
            unsigned c = excl;
            unsigned hh[4] = {h0, h1, h2, h3};
#pragma unroll
            for (int j = 0; j < 4; j++) {
                c += hh[j];
                if (c >= K_SEL) { atomicMin(&selbin, 4*t + j); break; }
            }
        }
        __syncthreads();
        int Bsel = selbin;

#pragma unroll
        for (int q = 0; q < 8; q++) {
            if ((int)(fb[q] >> 19) <= Bsel) {
                unsigned pos = atomicAdd(&ccnt, 1u);
                if (pos < CAP)
                    cand[pos] = (((unsigned long long)fb[q]) << 32) | (unsigned)(t + q*1024);
            }
        }
        __syncthreads();
        unsigned cnt = min(ccnt, (unsigned)CAP);
        if (t >= cnt && t < CAP) cand[t] = 0x3F800000FFFFFFFFull;  // (1.0f, ~0)
        __syncthreads();

        // bitonic sort CAP keys ascending on (value_bits, idx) -> stable
        for (int k = 2; k <= CAP; k <<= 1) {
            for (int j = k >> 1; j > 0; j >>= 1) {
                if (t < CAP) {
                    int l = t ^ j;
                    if (l > t) {
                        unsigned long long x = cand[t], y = cand[l];
                        bool asc = ((t & k) == 0);
                        if ((x > y) == asc) { cand[t] = y; cand[l] = x; }
                    }
                }
                __syncthreads();
            }
        }

        // exclusive cumprod of sorted values (first CAP threads)
        float v = 1.0f;
        if (t < CAP) v = __uint_as_float((unsigned)(cand[t] >> 32));
        float *f0 = (float*)uscan0, *f1 = (float*)uscan1;
        if (t < CAP) f0[t] = v;
        __syncthreads();
        for (int off = 1; off < CAP; off <<= 1) {
            float x = 0.0f;
            if (t < CAP) { x = f0[t]; if (t >= off) x *= f0[t - off]; }
            __syncthreads();
            if (t < CAP) f1[t] = x;
            __syncthreads();
            float* tmp = f0; f0 = f1; f1 = tmp;
        }
        if (t < CAP) {
            float pre = (t == 0) ? 1.0f : f0[t - 1];
            unsigned idx = (unsigned)(cand[t] & 0xFFFFFFFFull);
            if (idx < NN)
                ws[O_ALLOC + (size_t)b * NN + idx] = (1.0f - v) * pre;
        }
    } else {
        // ================= DOTS role (256 rows per block) =================
        int d = blockIdx.x - BB;
        int b = d >> 5;                 // 32 chunks per batch
        int rowbase = (d & 31) << 8;    // *256
        int wave = t >> 6, lane = t & 63;
        int g  = lane >> 4;             // 4 rows per wave per iter
        int li = lane & 15;             // 16 lanes per row

        float4 k4[4];
#pragma unroll
        for (int k = 0; k < 4; k++)
            k4[k] = ((const float4*)(ws + O_KEY + b*WW))[li + k*16];
        float kn   = ws[O_KN + b];
        float beta = ws[O_BETA + b];

        float psum = 0.0f;
#pragma unroll
        for (int p = 0; p < 4; p++) {
            int n = rowbase + wave*16 + p*4 + g;
            const float4* mrow = (const float4*)(mem + ((size_t)b * NN + n) * WW);
            float dot = 0.0f, nn2 = 0.0f;
#pragma unroll
            for (int k = 0; k < 4; k++) {
                float4 m = mrow[li + k*16];
                dot += m.x*k4[k].x + m.y*k4[k].y + m.z*k4[k].z + m.w*k4[k].w;
                nn2 += m.x*m.x + m.y*m.y + m.z*m.z + m.w*m.w;
            }
#pragma unroll
            for (int off = 8; off > 0; off >>= 1) {
                dot += __shfl_xor(dot, off, 64);
                nn2 += __shfl_xor(nn2, off, 64);
            }
            if (li == 0) {
                float pv = expf(dot / (kn * sqrtf(nn2) + EPSF) * beta);
                ws[O_S + (size_t)b * NN + n] = pv;
                psum += pv;
            }
        }
        if (li == 0) dred[wave*4 + g] = psum;
        __syncthreads();
        if (t == 0) {
            float s = 0.0f;
#pragma unroll
            for (int i = 0; i < 64; i++) s += dred[i];
            atomicAdd(&ws[O_SUM + b], s);
        }
    }
}

// ---------------- kernel 3: fused erase/add update ----------------
__global__ __launch_bounds__(256) void update_kernel(const float* __restrict__ mem,
                                                     const float* __restrict__ ws,
                                                     float* __restrict__ out) {
    int bid = gridDim.x - 1 - blockIdx.x;
    int b  = bid >> 7;
    int rb = (bid & 127) << 6;
    int wave = threadIdx.x >> 6, lane = threadIdx.x & 63;
    float4 e4 = ((const float4*)(ws + O_ERASE + b*WW))[lane];
    float4 a4 = ((const float4*)(ws + O_ADD + b*WW))[lane];
    float ag = ws[O_AG + b], wg = ws[O_WG + b];
    float iden = 1.0f / ws[O_SUM + b];
#pragma unroll 4
    for (int it = 0; it < 16; ++it) {
        int n = rb + it*4 + wave;
        size_t row = (size_t)b * NN + n;
        float pv  = ws[O_S + row];
        float al  = ws[O_ALLOC + row];
        float phi = ws[O_PHI + row];
        float cw  = pv * iden;
        float wwt = wg * (ag * al + (1.0f - ag) * cw);
        float4 m = ((const float4*)(mem + row * WW))[lane];
        floatx4 o;
        o.x = m.x * (1.0f - wwt * e4.x) * phi + wwt * a4.x;
        o.y = m.y * (1.0f - wwt * e4.y) * phi + wwt * a4.y;
        o.z = m.z * (1.0f - wwt * e4.z) * phi + wwt * a4.z;
        o.w = m.w * (1.0f - wwt * e4.w) * phi + wwt * a4.w;
        __builtin_nontemporal_store(o, &((floatx4*)(out + row * WW))[lane]);
    }
}

extern "C" void kernel_launch(void* const* d_in, const int* in_sizes, int n_in,
                              void* d_out, int out_size, void* d_ws, size_t ws_size,
                              hipStream_t stream) {
    const float* mem      = (const float*)d_in[0];
    const float* controls = (const float*)d_in[1];
    const float* rw       = (const float*)d_in[2];
    const float* us       = (const float*)d_in[3];
    const float* pw       = (const float*)d_in[4];
    float* out = (float*)d_out;
    float* ws  = (float*)d_ws;

    prep_kernel<<<BB, 256, 0, stream>>>(controls, ws);
    mid_kernel<<<BB + BB * (NN / 256), 1024, 0, stream>>>(mem, rw, us, pw, ws);
    update_kernel<<<BB * (NN / 64), 256, 0, stream>>>(mem, ws, out);
}

// Round 6
// 142.227 us; speedup vs baseline: 1.1906x; 1.0179x over previous
//
#include <hip/hip_runtime.h>
#include <math.h>

#define BB 32
#define NN 8192
#define WW 256
#define RR 4
#define CDIM (3*WW + RR + 3)   // 775
#define EPSF 1e-8f

#define K_SEL 128
#define CAP   256

typedef float floatx4 __attribute__((ext_vector_type(4)));

// ---- workspace layout (float offsets) ----
#define O_S      0                      // B*N : p = exp(beta*cossim)
#define O_PHI    (O_S     + BB*NN)      // B*N
#define O_ALLOC  (O_PHI   + BB*NN)      // B*N
#define O_PSUM   (O_ALLOC + BB*NN)      // B*32 partial softmax sums

__device__ __forceinline__ float sigmoidf_(float x) { return 1.0f / (1.0f + expf(-x)); }

// ------- kernel 1: role-split. blocks 0..31: phi/usc/topk/alloc.
//                   blocks 32..1055: dots -> p, per-chunk partial sums. -------
__global__ __launch_bounds__(1024) void mid_kernel(const float* __restrict__ mem,
                                                   const float* __restrict__ controls,
                                                   const float* __restrict__ rw,
                                                   const float* __restrict__ us,
                                                   const float* __restrict__ pw,
                                                   float* __restrict__ ws) {
    __shared__ unsigned hist[4096];            // 16 KB (topk role)
    __shared__ unsigned long long cand[CAP];   //  2 KB
    __shared__ unsigned uscan0[1024];          //  4 KB
    __shared__ unsigned uscan1[1024];          //  4 KB
    __shared__ float    dred[64];              // dots role
    __shared__ int selbin;
    __shared__ unsigned ccnt;

    int t = threadIdx.x;

    if (blockIdx.x < BB) {
        // ================= TOP-K role (one block per batch) =================
        int b = blockIdx.x;
        const float* c = controls + (size_t)b * CDIM;
        float fg[RR];
#pragma unroll
        for (int r = 0; r < RR; r++) fg[r] = sigmoidf_(c[3*WW + r]);

        for (int i = t; i < 4096; i += 1024) hist[i] = 0;
        if (t == 0) { selbin = 0x7FFFFFFF; ccnt = 0; }
        __syncthreads();

        unsigned fb[8];
#pragma unroll
        for (int q = 0; q < 8; q++) {
            int n = t + q * 1024;
            size_t gid = (size_t)b * NN + n;
            float phi = 1.0f;
#pragma unroll
            for (int r = 0; r < RR; r++)
                phi *= (1.0f - fg[r] * rw[((size_t)(b*RR + r)) * NN + n]);
            float u0 = us[gid];
            float u = (u0 + pw[gid] * (1.0f - u0)) * phi;
            float usc = u * (1.0f - EPSF) + EPSF;   // strictly positive, <= 1
            ws[O_PHI   + gid] = phi;
            ws[O_ALLOC + gid] = 0.0f;               // scatter fills top-K below
            fb[q] = __float_as_uint(usc);           // bits monotone for +floats
            atomicAdd(&hist[fb[q] >> 19], 1u);
        }
        __syncthreads();

        // cumulative over 4096 bins (4 bins/thread + 1024-scan)
        unsigned h0 = hist[4*t], h1 = hist[4*t+1], h2 = hist[4*t+2], h3 = hist[4*t+3];
        unsigned tot = h0 + h1 + h2 + h3;
        unsigned *a0 = uscan0, *a1 = uscan1;
        a0[t] = tot;
        __syncthreads();
        for (int off = 1; off < 1024; off <<= 1) {
            unsigned v = a0[t];
            if (t >= off) v += a0[t - off];
            a1[t] = v;
            __syncthreads();
            unsigned* tmp = a0; a0 = a1; a1 = tmp;
        }
        unsigned excl = (t == 0) ? 0u : a0[t - 1];
        {
            unsigned cc = excl;
            unsigned hh[4] = {h0, h1, h2, h3};
#pragma unroll
            for (int j = 0; j < 4; j++) {
                cc += hh[j];
                if (cc >= K_SEL) { atomicMin(&selbin, 4*t + j); break; }
            }
        }
        __syncthreads();
        int Bsel = selbin;

#pragma unroll
        for (int q = 0; q < 8; q++) {
            if ((int)(fb[q] >> 19) <= Bsel) {
                unsigned pos = atomicAdd(&ccnt, 1u);
                if (pos < CAP)
                    cand[pos] = (((unsigned long long)fb[q]) << 32) | (unsigned)(t + q*1024);
            }
        }
        __syncthreads();
        unsigned cnt = min(ccnt, (unsigned)CAP);
        if (t >= cnt && t < CAP) cand[t] = 0x3F800000FFFFFFFFull;  // (1.0f, ~0)
        __syncthreads();

        // bitonic sort CAP keys ascending on (value_bits, idx) -> stable
        for (int k = 2; k <= CAP; k <<= 1) {
            for (int j = k >> 1; j > 0; j >>= 1) {
                if (t < CAP) {
                    int l = t ^ j;
                    if (l > t) {
                        unsigned long long x = cand[t], y = cand[l];
                        bool asc = ((t & k) == 0);
                        if ((x > y) == asc) { cand[t] = y; cand[l] = x; }
                    }
                }
                __syncthreads();
            }
        }

        // exclusive cumprod of sorted values (first CAP threads)
        float v = 1.0f;
        if (t < CAP) v = __uint_as_float((unsigned)(cand[t] >> 32));
        float *f0 = (float*)uscan0, *f1 = (float*)uscan1;
        if (t < CAP) f0[t] = v;
        __syncthreads();
        for (int off = 1; off < CAP; off <<= 1) {
            float x = 0.0f;
            if (t < CAP) { x = f0[t]; if (t >= off) x *= f0[t - off]; }
            __syncthreads();
            if (t < CAP) f1[t] = x;
            __syncthreads();
            float* tmp = f0; f0 = f1; f1 = tmp;
        }
        if (t < CAP) {
            float pre = (t == 0) ? 1.0f : f0[t - 1];
            unsigned idx = (unsigned)(cand[t] & 0xFFFFFFFFull);
            if (idx < NN)
                ws[O_ALLOC + (size_t)b * NN + idx] = (1.0f - v) * pre;
        }
    } else {
        // ================= DOTS role (256 rows per block) =================
        int d = blockIdx.x - BB;
        int b = d >> 5;                 // 32 chunks per batch
        int rowbase = (d & 31) << 8;    // *256
        int wave = t >> 6, lane = t & 63;
        int g  = lane >> 4;             // 4 rows per wave per iter
        int li = lane & 15;             // 16 lanes per row

        const float* c = controls + (size_t)b * CDIM;
        // key fragment: lane li holds floats [li*4 + k*64 .. +3], k=0..3
        float4 k4[4];
        float ksq = 0.0f;
#pragma unroll
        for (int k = 0; k < 4; k++) {
            k4[k].x = c[li*4 + k*64 + 0];
            k4[k].y = c[li*4 + k*64 + 1];
            k4[k].z = c[li*4 + k*64 + 2];
            k4[k].w = c[li*4 + k*64 + 3];
            ksq += k4[k].x*k4[k].x + k4[k].y*k4[k].y + k4[k].z*k4[k].z + k4[k].w*k4[k].w;
        }
#pragma unroll
        for (int off = 8; off > 0; off >>= 1) ksq += __shfl_xor(ksq, off, 64);
        float kn = sqrtf(ksq);
        float bx = c[3*WW + RR];
        float beta = 1.0f + fmaxf(bx, 0.0f) + log1pf(expf(-fabsf(bx)));

        float psum = 0.0f;
#pragma unroll
        for (int p = 0; p < 4; p++) {
            int n = rowbase + wave*16 + p*4 + g;
            const float4* mrow = (const float4*)(mem + ((size_t)b * NN + n) * WW);
            float dot = 0.0f, nn2 = 0.0f;
#pragma unroll
            for (int k = 0; k < 4; k++) {
                float4 m = mrow[li + k*16];
                dot += m.x*k4[k].x + m.y*k4[k].y + m.z*k4[k].z + m.w*k4[k].w;
                nn2 += m.x*m.x + m.y*m.y + m.z*m.z + m.w*m.w;
            }
#pragma unroll
            for (int off = 8; off > 0; off >>= 1) {
                dot += __shfl_xor(dot, off, 64);
                nn2 += __shfl_xor(nn2, off, 64);
            }
            if (li == 0) {
                float pv = expf(dot / (kn * sqrtf(nn2) + EPSF) * beta);
                ws[O_S + (size_t)b * NN + n] = pv;
                psum += pv;
            }
        }
        if (li == 0) dred[wave*4 + g] = psum;
        __syncthreads();
        if (t == 0) {
            float s = 0.0f;
#pragma unroll
            for (int i = 0; i < 64; i++) s += dred[i];
            ws[O_PSUM + b*32 + (d & 31)] = s;
        }
    }
}

// ---------------- kernel 2: fused erase/add update (reverse order) ----------------
__global__ __launch_bounds__(256) void update_kernel(const float* __restrict__ mem,
                                                     const float* __restrict__ controls,
                                                     const float* __restrict__ ws,
                                                     float* __restrict__ out) {
    int bid = gridDim.x - 1 - blockIdx.x;     // reverse: reuse L3-resident tail of mem
    int b  = bid >> 7;
    int rb = (bid & 127) << 6;
    int wave = threadIdx.x >> 6, lane = threadIdx.x & 63;

    const float* c = controls + (size_t)b * CDIM;
    float4 e4, a4;
    e4.x = sigmoidf_(c[WW + lane*4 + 0]);
    e4.y = sigmoidf_(c[WW + lane*4 + 1]);
    e4.z = sigmoidf_(c[WW + lane*4 + 2]);
    e4.w = sigmoidf_(c[WW + lane*4 + 3]);
    a4.x = c[2*WW + lane*4 + 0];
    a4.y = c[2*WW + lane*4 + 1];
    a4.z = c[2*WW + lane*4 + 2];
    a4.w = c[2*WW + lane*4 + 3];
    float ag = sigmoidf_(c[3*WW + RR + 1]);
    float wg = sigmoidf_(c[3*WW + RR + 2]);

    float sum = 0.0f;
#pragma unroll
    for (int i = 0; i < 32; i++) sum += ws[O_PSUM + b*32 + i];
    float iden = 1.0f / sum;

#pragma unroll 4
    for (int it = 0; it < 16; ++it) {
        int n = rb + it*4 + wave;
        size_t row = (size_t)b * NN + n;
        float pv  = ws[O_S + row];
        float al  = ws[O_ALLOC + row];
        float phi = ws[O_PHI + row];
        float cw  = pv * iden;
        float wwt = wg * (ag * al + (1.0f - ag) * cw);
        float4 m = ((const float4*)(mem + row * WW))[lane];
        floatx4 o;
        o.x = m.x * (1.0f - wwt * e4.x) * phi + wwt * a4.x;
        o.y = m.y * (1.0f - wwt * e4.y) * phi + wwt * a4.y;
        o.z = m.z * (1.0f - wwt * e4.z) * phi + wwt * a4.z;
        o.w = m.w * (1.0f - wwt * e4.w) * phi + wwt * a4.w;
        __builtin_nontemporal_store(o, &((floatx4*)(out + row * WW))[lane]);
    }
}

extern "C" void kernel_launch(void* const* d_in, const int* in_sizes, int n_in,
                              void* d_out, int out_size, void* d_ws, size_t ws_size,
                              hipStream_t stream) {
    const float* mem      = (const float*)d_in[0];
    const float* controls = (const float*)d_in[1];
    const float* rw       = (const float*)d_in[2];
    const float* us       = (const float*)d_in[3];
    const float* pw       = (const float*)d_in[4];
    float* out = (float*)d_out;
    float* ws  = (float*)d_ws;

    mid_kernel<<<BB + BB * (NN / 256), 1024, 0, stream>>>(mem, controls, rw, us, pw, ws);
    update_kernel<<<BB * (NN / 64), 256, 0, stream>>>(mem, controls, ws, out);
}